// Round 7
// baseline (69.149 us; speedup 1.0000x reference)
//
#include <hip/hip_runtime.h>
#include <math.h>

#define H 256
#define W 256
#define HW (H * W)
#define CH 24
#define NK 63
#define PXS 40          // LDS B-tile per-pixel stride in shorts (80 B)
#define KSTEPS 25       // K = 25 taps * 32 (24 ch + 8 zero-pad)

typedef short v8s __attribute__((ext_vector_type(8)));
typedef short v4s __attribute__((ext_vector_type(4)));
typedef float v4f __attribute__((ext_vector_type(4)));

// ---------------- RBF helpers: 9-tap window (J=+/-4) -------------------------
__device__ __forceinline__ float rbf_val(float v, const float* ms, const float* ws,
                                         int ch, float m0, float inv_step) {
    int kc = (int)floorf((v - m0) * inv_step + 0.5f);
    kc = min(max(kc, 4), NK - 5);
    float s = 0.f;
    #pragma unroll
    for (int j = 0; j < 9; ++j) {
        int k = kc - 4 + j;
        float d = v - ms[k];
        s = fmaf(__expf(d * d * -0.005f), ws[ch * NK + k], s);
    }
    return s;
}
__device__ __forceinline__ float rbf_der(float v, const float* ms, const float* ws,
                                         int ch, float m0, float inv_step) {
    int kc = (int)floorf((v - m0) * inv_step + 0.5f);
    kc = min(max(kc, 4), NK - 5);
    float s = 0.f;
    #pragma unroll
    for (int j = 0; j < 9; ++j) {
        int k = kc - 4 + j;
        float d = v - ms[k];
        s = fmaf(__expf(d * d * -0.005f) * d * -0.01f, ws[ch * NK + k], s);
    }
    return s;
}

__device__ __forceinline__ short f2bf(float v) {
    unsigned u = __float_as_uint(v);
    u += 0x7fff + ((u >> 16) & 1);
    return (short)(u >> 16);
}

// ---------------- prep: norms, f0n/f0t, MFMA A-fragment pack ------------------
// Abuf: [mode 2][mtile 2][kstep 25][lane 64] v8s. k = tap*32 + c (c<24, pad 0).
__global__ void k_prep(const float* __restrict__ f0, const float* __restrict__ f1,
                       float* __restrict__ f0n, float* __restrict__ f0t,
                       v8s* __restrict__ abuf) {
    __shared__ float red[256];
    int tid = threadIdx.x;
    float s1 = 0.f;
    for (int i = tid; i < 14400; i += 256) s1 += f1[i] * f1[i];
    red[tid] = s1; __syncthreads();
    for (int off = 128; off; off >>= 1) { if (tid < off) red[tid] += red[tid + off]; __syncthreads(); }
    float inv1 = 1.f / sqrtf(red[0]);
    __syncthreads();
    if (blockIdx.x == 0) {
        float s0 = 0.f;
        for (int i = tid; i < 600; i += 256) s0 += f0[i] * f0[i];
        red[tid] = s0; __syncthreads();
        for (int off = 128; off; off >>= 1) { if (tid < off) red[tid] += red[tid + off]; __syncthreads(); }
        float inv0 = 1.f / sqrtf(red[0]);
        for (int i = tid; i < 600; i += 256) {
            int c = i / 25, k = i % 25;
            f0n[i] = f0[i] * inv0;
            f0t[i] = f0[c * 25 + (24 - k)] * inv0;
        }
    }
    // 6400 jobs = 25 blocks x 256 threads
    int gid = blockIdx.x * 256 + tid;
    int lane = gid & 63;
    int rest = gid >> 6;          // 0..99
    int s = rest % KSTEPS;        // tap
    int md = rest / KSTEPS;       // 0..3
    int mode = md >> 1, m = md & 1;
    int o = m * 16 + (lane & 15);
    v8s av;
    #pragma unroll
    for (int j = 0; j < 8; ++j) {
        int c = 8 * (lane >> 4) + j;   // 0..31
        float wv = 0.f;
        if (o < CH && c < CH) {
            wv = (mode == 0) ? f1[(o * CH + c) * 25 + s]
                             : f1[(c * CH + o) * 25 + (24 - s)];
            wv *= inv1;
        }
        av[j] = f2bf(wv);
    }
    abuf[gid] = av;
}

// ---------------- fused A: conv1+rbf0 -> conv2 MFMA + rbf1 -------------------
// 8x8 output tile, 4 waves, grid 32x32. t1: 12x12 haloed region, stride-40 bf16.
__global__ __launch_bounds__(256, 4) void k_fuseA(const float* __restrict__ x,
        const float* __restrict__ f0n, const v8s* __restrict__ abuf,
        const float* __restrict__ mean, const float* __restrict__ aw0,
        const float* __restrict__ aw1, short* __restrict__ tb) {
    __shared__ float xs[16 * 16];
    __shared__ __align__(16) short t1[144 * PXS];   // 11520 B
    __shared__ float ms[NK];
    __shared__ float ws0[CH * NK];
    __shared__ float ws1[CH * NK];
    int tid = threadIdx.x;
    int x0 = blockIdx.x * 8, y0 = blockIdx.y * 8;
    {   // stage x window (clamped = replication pad)
        int r = tid >> 4, cL = tid & 15;
        int gy = min(max(y0 + r - 4, 0), H - 1);
        int gx = min(max(x0 + cL - 4, 0), W - 1);
        xs[tid] = x[gy * W + gx];
    }
    for (int i = tid; i < NK; i += 256) ms[i] = mean[i];
    for (int i = tid; i < CH * NK; i += 256) { ws0[i] = aw0[i]; ws1[i] = aw1[i]; }
    __syncthreads();
    float m0 = ms[0];
    float inv_step = (float)(NK - 1) / (ms[NK - 1] - m0);

    // stage 1: t1 = rbf0(conv1) on 12x12 haloed region
    if (tid < 144) {
        int yi = (tid * 5462) >> 16;        // tid / 12
        int xi = tid - yi * 12;
        int sy = min(max(y0 + yi - 2, 0), H - 1);
        int sx = min(max(x0 + xi - 2, 0), W - 1);
        int iy[5], ix[5];
        #pragma unroll
        for (int u = 0; u < 5; ++u) {
            iy[u] = min(max(sy + u - 2, 0), H - 1) - (y0 - 4);
            ix[u] = min(max(sx + u - 2, 0), W - 1) - (x0 - 4);
        }
        float in_[25];
        #pragma unroll
        for (int u = 0; u < 5; ++u)
            #pragma unroll
            for (int v = 0; v < 5; ++v) in_[u * 5 + v] = xs[iy[u] * 16 + ix[v]];
        #pragma unroll 1
        for (int og = 0; og < 3; ++og) {
            v8s pk;
            #pragma unroll
            for (int oj = 0; oj < 8; ++oj) {
                int o = og * 8 + oj;
                float a = 0.f;
                #pragma unroll
                for (int k = 0; k < 25; ++k) a = fmaf(in_[k], f0n[o * 25 + k], a);
                pk[oj] = f2bf(rbf_val(a, ms, ws0, o, m0, inv_step));
            }
            *(v8s*)&t1[tid * PXS + og * 8] = pk;
        }
        v8s z = {0,0,0,0,0,0,0,0};
        *(v8s*)&t1[tid * PXS + 24] = z;     // zero-pad c 24..31
    }
    __syncthreads();

    // stage 2: conv2 MFMA; wave = one 16-px N-tile (2 rows of 8)
    int lane = tid & 63, wv_ = tid >> 6;
    int p = lane & 15, q = lane >> 4;
    int row = (wv_ * 16 + p) >> 3, col = p & 7;
    const short* bbase = &t1[(row * 12 + col) * PXS + q * 8];
    v4f a0v = {0.f,0.f,0.f,0.f}, a1v = {0.f,0.f,0.f,0.f};
    #pragma unroll
    for (int s = 0; s < KSTEPS; ++s) {
        const int u = s / 5, v = s % 5;     // compile-time under full unroll
        v8s b   = *(const v8s*)&bbase[(u * 12 + v) * PXS];
        v8s af0 = abuf[s * 64 + lane];
        v8s af1 = abuf[1600 + s * 64 + lane];
        a0v = __builtin_amdgcn_mfma_f32_16x16x32_bf16(af0, b, a0v, 0, 0, 0);
        a1v = __builtin_amdgcn_mfma_f32_16x16x32_bf16(af1, b, a1v, 0, 0, 0);
    }
    // epilogue: rbf1 -> tb[pix][ch] (channel-minor), 8B stores
    int pix = (y0 + row) * W + (x0 + col);
    v4s st;
    #pragma unroll
    for (int j = 0; j < 4; ++j)
        st[j] = f2bf(rbf_val(a0v[j], ms, ws1, q * 4 + j, m0, inv_step));
    *(v4s*)&tb[pix * 24 + q * 4] = st;
    if (q < 2) {
        #pragma unroll
        for (int j = 0; j < 4; ++j)
            st[j] = f2bf(rbf_val(a1v[j], ms, ws1, 16 + q * 4 + j, m0, inv_step));
        *(v4s*)&tb[pix * 24 + 16 + q * 4] = st;
    }
}

// ---------------- fused B: convT2 MFMA + rbf' -> convT1 + final --------------
// 8x8 output tile. tbt: 16x16 window (zero pad), stride-40 bf16.
// t3: 12x12 region, stride 25 f32. 9 N-tiles; wave w owns tiles 3w..3w+2.
__global__ __launch_bounds__(256, 3) void k_fuseB(const short* __restrict__ tb,
        const v8s* __restrict__ abuf, const float* __restrict__ f0t,
        const float* __restrict__ mean, const float* __restrict__ aw0,
        const float* __restrict__ x, const float* __restrict__ y,
        const float* __restrict__ lamp, float* __restrict__ out) {
    __shared__ __align__(16) short tbt[256 * PXS];  // 20480 B (reused as red[])
    __shared__ float t3[144 * 25];                  // 14400 B
    __shared__ float ms[NK];
    __shared__ float ws[CH * NK];
    int tid = threadIdx.x;
    int x0 = blockIdx.x * 8, y0 = blockIdx.y * 8;
    {   // stage tb window: 16x16 px, zero pad outside image
        int r = tid >> 4, cL = tid & 15;
        int gy = y0 + r - 4, gx = x0 + cL - 4;
        v8s z = {0,0,0,0,0,0,0,0};
        if (gy >= 0 && gy < H && gx >= 0 && gx < W) {
            const v8s* src = (const v8s*)&tb[(gy * W + gx) * 24];
            *(v8s*)&tbt[tid * PXS]      = src[0];
            *(v8s*)&tbt[tid * PXS + 8]  = src[1];
            *(v8s*)&tbt[tid * PXS + 16] = src[2];
        } else {
            *(v8s*)&tbt[tid * PXS]      = z;
            *(v8s*)&tbt[tid * PXS + 8]  = z;
            *(v8s*)&tbt[tid * PXS + 16] = z;
        }
        *(v8s*)&tbt[tid * PXS + 24] = z;            // zero-pad c 24..31
    }
    for (int i = tid; i < NK; i += 256) ms[i] = mean[i];
    for (int i = tid; i < CH * NK; i += 256) ws[i] = aw0[i];
    __syncthreads();
    float m0 = ms[0];
    float inv_step = (float)(NK - 1) / (ms[NK - 1] - m0);

    // convT2 MFMA (mode-1 A-frags): wave w owns tiles 3w..3w+2 (w=3 discarded)
    int lane = tid & 63, wv_ = tid >> 6;
    int p = lane & 15, q = lane >> 4;
    const v8s* ap = abuf + 3200;
    int base[3], frow[3], fcol[3];
    bool valid[3];
    #pragma unroll
    for (int g = 0; g < 3; ++g) {
        int tIdx = wv_ * 3 + g;
        valid[g] = (tIdx <= 8);
        int tc = valid[g] ? tIdx : 8;
        int f = tc * 16 + p;                 // flat t3 px < 144
        int r_ = (f * 5462) >> 16;           // f / 12
        frow[g] = r_; fcol[g] = f - r_ * 12;
        base[g] = (r_ * 16 + fcol[g]) * PXS + q * 8;
    }
    v4f acc0[3], acc1[3];
    #pragma unroll
    for (int g = 0; g < 3; ++g) { acc0[g] = (v4f){0.f,0.f,0.f,0.f}; acc1[g] = (v4f){0.f,0.f,0.f,0.f}; }
    #pragma unroll
    for (int s = 0; s < KSTEPS; ++s) {
        const int off = ((s / 5) * 16 + (s % 5)) * PXS;   // compile-time
        v8s af0 = ap[s * 64 + lane];
        v8s af1 = ap[1600 + s * 64 + lane];
        #pragma unroll
        for (int g = 0; g < 3; ++g) {
            v8s b = *(const v8s*)&tbt[base[g] + off];
            acc0[g] = __builtin_amdgcn_mfma_f32_16x16x32_bf16(af0, b, acc0[g], 0, 0, 0);
            acc1[g] = __builtin_amdgcn_mfma_f32_16x16x32_bf16(af1, b, acc1[g], 0, 0, 0);
        }
    }
    // rbf_der -> t3 (zero outside image)
    #pragma unroll
    for (int g = 0; g < 3; ++g) {
        if (valid[g]) {
            int f = (wv_ * 3 + g) * 16 + p;
            int gy = y0 + frow[g] - 2, gx = x0 + fcol[g] - 2;
            bool inimg = (gy >= 0 && gy < H && gx >= 0 && gx < W);
            #pragma unroll
            for (int j = 0; j < 4; ++j)
                t3[f * 25 + q * 4 + j] = inimg ? rbf_der(acc0[g][j], ms, ws, q * 4 + j, m0, inv_step) : 0.f;
            if (q < 2) {
                #pragma unroll
                for (int j = 0; j < 4; ++j)
                    t3[f * 25 + 16 + q * 4 + j] = inimg ? rbf_der(acc1[g][j], ms, ws, 16 + q * 4 + j, m0, inv_step) : 0.f;
            }
        }
    }
    __syncthreads();   // tbt fully consumed; reuse as reduction buffer

    // convT1 (24->1, pre-flipped f0t) + final; 4-way channel split across waves
    float* red = (float*)tbt;
    int g = __builtin_amdgcn_readfirstlane(tid >> 6);
    int px = tid & 63, pr = px >> 3, pc = px & 7;
    float a = 0.f;
    #pragma unroll 1
    for (int cc = 0; cc < 6; ++cc) {
        int c = g * 6 + cc;
        const float* fb = f0t + c * 25;
        #pragma unroll
        for (int u = 0; u < 5; ++u)
            #pragma unroll
            for (int v = 0; v < 5; ++v)
                a = fmaf(t3[((pr + u) * 12 + (pc + v)) * 25 + c], fb[u * 5 + v], a);
    }
    red[tid] = a;
    __syncthreads();
    if (tid < 64) {
        float tot = red[tid] + red[64 + tid] + red[128 + tid] + red[192 + tid];
        int pix = (y0 + pr) * W + (x0 + pc);
        float elam = __expf(lamp[0]);
        float xv = x[pix], yv = y[pix];
        out[pix] = xv - (tot + elam * (xv - yv));
    }
}

extern "C" void kernel_launch(void* const* d_in, const int* in_sizes, int n_in,
                              void* d_out, int out_size, void* d_ws, size_t ws_size,
                              hipStream_t stream) {
    const float* x    = (const float*)d_in[0];
    const float* y    = (const float*)d_in[1];
    const float* f0   = (const float*)d_in[3];
    const float* f1   = (const float*)d_in[4];
    const float* aw0  = (const float*)d_in[5];
    const float* aw1  = (const float*)d_in[6];
    const float* mean = (const float*)d_in[7];
    const float* lamp = (const float*)d_in[8];
    float* out = (float*)d_out;

    float* w   = (float*)d_ws;
    float* f0n = w;                  // 600
    float* f0t = w + 640;            // 600
    v8s*  abuf = (v8s*)(w + 1536);   // 6400 * 16 B = 102400 B
    short* tb  = (short*)(w + 32768);

    k_prep<<<25, 256, 0, stream>>>(f0, f1, f0n, f0t, abuf);
    dim3 grid(W / 8, H / 8);         // 32 x 32 = 1024 blocks
    k_fuseA<<<grid, 256, 0, stream>>>(x, f0n, abuf, mean, aw0, aw1, tb);
    k_fuseB<<<grid, 256, 0, stream>>>(tb, abuf, f0t, mean, aw0, x, y, lamp, out);
}

// Round 8
// 62.103 us; speedup vs baseline: 1.1135x; 1.1135x over previous
//
#include <hip/hip_runtime.h>
#include <math.h>

#define H 256
#define W 256
#define HW (H * W)
#define CH 24
#define NK 63
#define PXS 40          // LDS B-tile per-pixel stride in shorts (80 B)
#define KSTEPS 25       // K = 25 taps * 32 (24 ch + 8 zero-pad)
#define T3S 26          // t3 per-pixel stride in floats (8B-aligned ch pairs)

typedef short v8s __attribute__((ext_vector_type(8)));
typedef short v4s __attribute__((ext_vector_type(4)));
typedef float v4f __attribute__((ext_vector_type(4)));

// ---------------- analytic RBF: exp(-a(t-k)^2) = exp(-a f^2) e^{2af j} G_j ---
struct RbfCtx {
    float m0, istep, c2a, ahalf, dfac;
    float G1, G2, G3, G4;      // exp(-a j^2), j=1..4
};
__device__ __forceinline__ RbfCtx make_ctx(const float* __restrict__ mean) {
    RbfCtx c;
    c.m0 = mean[0];
    float m62 = mean[NK - 1];
    float step = (m62 - c.m0) * (1.f / (float)(NK - 1));
    c.istep = (float)(NK - 1) / (m62 - c.m0);
    float a = step * step * (1.f / 200.f);      // = 0.5 for step 10
    c.c2a = 2.f * a;
    c.ahalf = a;
    c.dfac = -step * 0.01f;
    c.G1 = __expf(-a);
    c.G2 = __expf(-4.f * a);
    c.G3 = __expf(-9.f * a);
    c.G4 = __expf(-16.f * a);
    return c;
}

// DER=false: sum_k w_k exp(-(v-m_k)^2/200)
// DER=true : sum_k w_k exp(-(v-m_k)^2/200) (v-m_k)(-1/100)
template<bool DER>
__device__ __forceinline__ float rbf_eval(float v, const float* __restrict__ wrow,
                                          const RbfCtx& c) {
    float t = (v - c.m0) * c.istep;
    float kcf = floorf(t + 0.5f);
    kcf = fminf(fmaxf(kcf, 4.f), (float)(NK - 5));
    int kc = (int)kcf;
    float f = t - kcf;
    f = fminf(fmaxf(f, -12.f), 12.f);           // only active when kc clamped (true val ~0)
    float g  = c.c2a * f;
    float E1 = __expf(g), R1 = __expf(-g);
    float E2 = E1 * E1, R2 = R1 * R1;
    float gpm4 = c.G4 * R2 * R2;
    float gpm3 = c.G3 * R2 * R1;
    float gpm2 = c.G2 * R2;
    float gpm1 = c.G1 * R1;
    float gpp1 = c.G1 * E1;
    float gpp2 = c.G2 * E2;
    float gpp3 = c.G3 * E2 * E1;
    float gpp4 = c.G4 * E2 * E2;
    const float* p = wrow + (kc - 4);
    float m_m4 = p[0] * gpm4, m_m3 = p[1] * gpm3, m_m2 = p[2] * gpm2, m_m1 = p[3] * gpm1;
    float m_0  = p[4];
    float m_p1 = p[5] * gpp1, m_p2 = p[6] * gpp2, m_p3 = p[7] * gpp3, m_p4 = p[8] * gpp4;
    float S0 = ((m_m4 + m_m3) + (m_m2 + m_m1)) + m_0 + ((m_p1 + m_p2) + (m_p3 + m_p4));
    float base = __expf(-c.ahalf * f * f);
    if (!DER) return base * S0;
    float S1 = 0.f;
    S1 = fmaf(m_m4, -4.f, S1); S1 = fmaf(m_m3, -3.f, S1);
    S1 = fmaf(m_m2, -2.f, S1); S1 = fmaf(m_m1, -1.f, S1);
    S1 = fmaf(m_p1,  1.f, S1); S1 = fmaf(m_p2,  2.f, S1);
    S1 = fmaf(m_p3,  3.f, S1); S1 = fmaf(m_p4,  4.f, S1);
    return c.dfac * base * fmaf(f, S0, -S1);
}

__device__ __forceinline__ short f2bf(float v) {
    unsigned u = __float_as_uint(v);
    u += 0x7fff + ((u >> 16) & 1);
    return (short)(u >> 16);
}

// ---------------- prep: norms, f0n/f0t, MFMA A-fragment pack ------------------
// Abuf: [mode 2][mtile 2][kstep 25][lane 64] v8s. k = tap*32 + c (c<24, pad 0).
__global__ void k_prep(const float* __restrict__ f0, const float* __restrict__ f1,
                       float* __restrict__ f0n, float* __restrict__ f0t,
                       v8s* __restrict__ abuf) {
    __shared__ float red[256];
    int tid = threadIdx.x;
    float s1 = 0.f;
    for (int i = tid; i < 14400; i += 256) s1 += f1[i] * f1[i];
    red[tid] = s1; __syncthreads();
    for (int off = 128; off; off >>= 1) { if (tid < off) red[tid] += red[tid + off]; __syncthreads(); }
    float inv1 = 1.f / sqrtf(red[0]);
    __syncthreads();
    if (blockIdx.x == 0) {
        float s0 = 0.f;
        for (int i = tid; i < 600; i += 256) s0 += f0[i] * f0[i];
        red[tid] = s0; __syncthreads();
        for (int off = 128; off; off >>= 1) { if (tid < off) red[tid] += red[tid + off]; __syncthreads(); }
        float inv0 = 1.f / sqrtf(red[0]);
        for (int i = tid; i < 600; i += 256) {
            int c = i / 25, k = i % 25;
            f0n[i] = f0[i] * inv0;
            f0t[i] = f0[c * 25 + (24 - k)] * inv0;
        }
    }
    // 6400 jobs = 25 blocks x 256 threads
    int gid = blockIdx.x * 256 + tid;
    int lane = gid & 63;
    int rest = gid >> 6;          // 0..99
    int s = rest % KSTEPS;        // tap
    int md = rest / KSTEPS;       // 0..3
    int mode = md >> 1, m = md & 1;
    int o = m * 16 + (lane & 15);
    v8s av;
    #pragma unroll
    for (int j = 0; j < 8; ++j) {
        int c = 8 * (lane >> 4) + j;   // 0..31
        float wv = 0.f;
        if (o < CH && c < CH) {
            wv = (mode == 0) ? f1[(o * CH + c) * 25 + s]
                             : f1[(c * CH + o) * 25 + (24 - s)];
            wv *= inv1;
        }
        av[j] = f2bf(wv);
    }
    abuf[gid] = av;
}

// ---------------- fused A: conv1+rbf0 -> conv2 MFMA + rbf1 -------------------
// 8x8 output tile, 4 waves, grid 32x32. t1: 12x12 haloed region, stride-40 bf16.
__global__ __launch_bounds__(256, 4) void k_fuseA(const float* __restrict__ x,
        const float* __restrict__ f0n, const v8s* __restrict__ abuf,
        const float* __restrict__ mean, const float* __restrict__ aw0,
        const float* __restrict__ aw1, short* __restrict__ tb) {
    __shared__ float xs[16 * 16];
    __shared__ __align__(16) short t1[144 * PXS];   // 11520 B
    __shared__ float ws0[CH * NK];
    __shared__ float ws1[CH * NK];
    int tid = threadIdx.x;
    int x0 = blockIdx.x * 8, y0 = blockIdx.y * 8;
    {   // stage x window (clamped = replication pad)
        int r = tid >> 4, cL = tid & 15;
        int gy = min(max(y0 + r - 4, 0), H - 1);
        int gx = min(max(x0 + cL - 4, 0), W - 1);
        xs[tid] = x[gy * W + gx];
    }
    for (int i = tid; i < CH * NK; i += 256) { ws0[i] = aw0[i]; ws1[i] = aw1[i]; }
    RbfCtx ctx = make_ctx(mean);
    __syncthreads();

    // stage 1: t1 = rbf0(conv1) on 12x12 haloed region
    if (tid < 144) {
        int yi = (tid * 5462) >> 16;        // tid / 12
        int xi = tid - yi * 12;
        int sy = min(max(y0 + yi - 2, 0), H - 1);
        int sx = min(max(x0 + xi - 2, 0), W - 1);
        int iy[5], ix[5];
        #pragma unroll
        for (int u = 0; u < 5; ++u) {
            iy[u] = min(max(sy + u - 2, 0), H - 1) - (y0 - 4);
            ix[u] = min(max(sx + u - 2, 0), W - 1) - (x0 - 4);
        }
        float in_[25];
        #pragma unroll
        for (int u = 0; u < 5; ++u)
            #pragma unroll
            for (int v = 0; v < 5; ++v) in_[u * 5 + v] = xs[iy[u] * 16 + ix[v]];
        #pragma unroll 1
        for (int og = 0; og < 3; ++og) {
            v8s pk;
            #pragma unroll
            for (int oj = 0; oj < 8; ++oj) {
                int o = og * 8 + oj;
                float a = 0.f;
                #pragma unroll
                for (int k = 0; k < 25; ++k) a = fmaf(in_[k], f0n[o * 25 + k], a);
                pk[oj] = f2bf(rbf_eval<false>(a, ws0 + o * NK, ctx));
            }
            *(v8s*)&t1[tid * PXS + og * 8] = pk;
        }
        v8s z = {0,0,0,0,0,0,0,0};
        *(v8s*)&t1[tid * PXS + 24] = z;     // zero-pad c 24..31
    }
    __syncthreads();

    // stage 2: conv2 MFMA; wave = one 16-px N-tile (2 rows of 8)
    int lane = tid & 63, wv_ = tid >> 6;
    int p = lane & 15, q = lane >> 4;
    int row = (wv_ * 16 + p) >> 3, col = p & 7;
    const short* bbase = &t1[(row * 12 + col) * PXS + q * 8];
    v4f a0v = {0.f,0.f,0.f,0.f}, a1v = {0.f,0.f,0.f,0.f};
    #pragma unroll
    for (int s = 0; s < KSTEPS; ++s) {
        const int u = s / 5, v = s % 5;     // compile-time under full unroll
        v8s b   = *(const v8s*)&bbase[(u * 12 + v) * PXS];
        v8s af0 = abuf[s * 64 + lane];
        v8s af1 = abuf[1600 + s * 64 + lane];
        a0v = __builtin_amdgcn_mfma_f32_16x16x32_bf16(af0, b, a0v, 0, 0, 0);
        a1v = __builtin_amdgcn_mfma_f32_16x16x32_bf16(af1, b, a1v, 0, 0, 0);
    }
    // epilogue: rbf1 -> tb[pix][ch] (channel-minor), 8B stores
    int pix = (y0 + row) * W + (x0 + col);
    v4s st;
    #pragma unroll
    for (int j = 0; j < 4; ++j)
        st[j] = f2bf(rbf_eval<false>(a0v[j], ws1 + (q * 4 + j) * NK, ctx));
    *(v4s*)&tb[pix * 24 + q * 4] = st;
    if (q < 2) {
        #pragma unroll
        for (int j = 0; j < 4; ++j)
            st[j] = f2bf(rbf_eval<false>(a1v[j], ws1 + (16 + q * 4 + j) * NK, ctx));
        *(v4s*)&tb[pix * 24 + 16 + q * 4] = st;
    }
}

// ---------------- fused B: convT2 MFMA + rbf' -> convT1 + final --------------
// 8x8 output tile. tbt: 16x16 window (zero pad), stride-40 bf16.
// t3: 12x12 region, stride 26 f32. 9 N-tiles; wave w owns tiles 3w..3w+2.
__global__ __launch_bounds__(256, 3) void k_fuseB(const short* __restrict__ tb,
        const v8s* __restrict__ abuf, const float* __restrict__ f0t,
        const float* __restrict__ mean, const float* __restrict__ aw0,
        const float* __restrict__ x, const float* __restrict__ y,
        const float* __restrict__ lamp, float* __restrict__ out) {
    __shared__ __align__(16) short tbt[256 * PXS];  // 20480 B (reused as red[])
    __shared__ float t3[144 * T3S];                 // 14976 B
    __shared__ float ws[CH * NK];
    int tid = threadIdx.x;
    int x0 = blockIdx.x * 8, y0 = blockIdx.y * 8;
    {   // stage tb window: 16x16 px, zero pad outside image
        int r = tid >> 4, cL = tid & 15;
        int gy = y0 + r - 4, gx = x0 + cL - 4;
        v8s z = {0,0,0,0,0,0,0,0};
        if (gy >= 0 && gy < H && gx >= 0 && gx < W) {
            const v8s* src = (const v8s*)&tb[(gy * W + gx) * 24];
            *(v8s*)&tbt[tid * PXS]      = src[0];
            *(v8s*)&tbt[tid * PXS + 8]  = src[1];
            *(v8s*)&tbt[tid * PXS + 16] = src[2];
        } else {
            *(v8s*)&tbt[tid * PXS]      = z;
            *(v8s*)&tbt[tid * PXS + 8]  = z;
            *(v8s*)&tbt[tid * PXS + 16] = z;
        }
        *(v8s*)&tbt[tid * PXS + 24] = z;            // zero-pad c 24..31
    }
    for (int i = tid; i < CH * NK; i += 256) ws[i] = aw0[i];
    RbfCtx ctx = make_ctx(mean);
    __syncthreads();

    // convT2 MFMA (mode-1 A-frags): wave w owns tiles 3w..3w+2 (w=3 partial)
    int lane = tid & 63, wv_ = tid >> 6;
    int p = lane & 15, q = lane >> 4;
    const v8s* ap = abuf + 3200;
    int base[3], frow[3], fcol[3];
    bool valid[3];
    #pragma unroll
    for (int g = 0; g < 3; ++g) {
        int tIdx = wv_ * 3 + g;
        valid[g] = (tIdx <= 8);
        int tc = valid[g] ? tIdx : 8;
        int f = tc * 16 + p;                 // flat t3 px < 144
        int r_ = (f * 5462) >> 16;           // f / 12
        frow[g] = r_; fcol[g] = f - r_ * 12;
        base[g] = (r_ * 16 + fcol[g]) * PXS + q * 8;
    }
    v4f acc0[3], acc1[3];
    #pragma unroll
    for (int g = 0; g < 3; ++g) { acc0[g] = (v4f){0.f,0.f,0.f,0.f}; acc1[g] = (v4f){0.f,0.f,0.f,0.f}; }
    #pragma unroll
    for (int s = 0; s < KSTEPS; ++s) {
        const int off = ((s / 5) * 16 + (s % 5)) * PXS;   // compile-time
        v8s af0 = ap[s * 64 + lane];
        v8s af1 = ap[1600 + s * 64 + lane];
        #pragma unroll
        for (int g = 0; g < 3; ++g) {
            v8s b = *(const v8s*)&tbt[base[g] + off];
            acc0[g] = __builtin_amdgcn_mfma_f32_16x16x32_bf16(af0, b, acc0[g], 0, 0, 0);
            acc1[g] = __builtin_amdgcn_mfma_f32_16x16x32_bf16(af1, b, acc1[g], 0, 0, 0);
        }
    }
    // rbf_der -> t3 (zero outside image)
    #pragma unroll
    for (int g = 0; g < 3; ++g) {
        if (valid[g]) {
            int f = (wv_ * 3 + g) * 16 + p;
            int gy = y0 + frow[g] - 2, gx = x0 + fcol[g] - 2;
            bool inimg = (gy >= 0 && gy < H && gx >= 0 && gx < W);
            #pragma unroll
            for (int j = 0; j < 4; ++j)
                t3[f * T3S + q * 4 + j] = inimg ? rbf_eval<true>(acc0[g][j], ws + (q * 4 + j) * NK, ctx) : 0.f;
            if (q < 2) {
                #pragma unroll
                for (int j = 0; j < 4; ++j)
                    t3[f * T3S + 16 + q * 4 + j] = inimg ? rbf_eval<true>(acc1[g][j], ws + (16 + q * 4 + j) * NK, ctx) : 0.f;
            }
        }
    }
    __syncthreads();   // tbt fully consumed; reuse as reduction buffer

    // convT1 (24->1, pre-flipped f0t) + final; 4-way channel split across waves
    float* red = (float*)tbt;
    int g = __builtin_amdgcn_readfirstlane(tid >> 6);
    int px = tid & 63, pr = px >> 3, pc = px & 7;
    float a = 0.f;
    #pragma unroll 1
    for (int cp = 0; cp < 3; ++cp) {
        int c = g * 6 + cp * 2;              // even -> 8B-aligned pairs
        const float* fb0 = f0t + c * 25;
        const float* fb1 = f0t + (c + 1) * 25;
        #pragma unroll
        for (int u = 0; u < 5; ++u)
            #pragma unroll
            for (int v = 0; v < 5; ++v) {
                float2 tp = *(const float2*)&t3[((pr + u) * 12 + (pc + v)) * T3S + c];
                a = fmaf(tp.x, fb0[u * 5 + v], a);
                a = fmaf(tp.y, fb1[u * 5 + v], a);
            }
    }
    red[tid] = a;
    __syncthreads();
    if (tid < 64) {
        float tot = red[tid] + red[64 + tid] + red[128 + tid] + red[192 + tid];
        int pix = (y0 + pr) * W + (x0 + pc);
        float elam = __expf(lamp[0]);
        float xv = x[pix], yv = y[pix];
        out[pix] = xv - (tot + elam * (xv - yv));
    }
}

extern "C" void kernel_launch(void* const* d_in, const int* in_sizes, int n_in,
                              void* d_out, int out_size, void* d_ws, size_t ws_size,
                              hipStream_t stream) {
    const float* x    = (const float*)d_in[0];
    const float* y    = (const float*)d_in[1];
    const float* f0   = (const float*)d_in[3];
    const float* f1   = (const float*)d_in[4];
    const float* aw0  = (const float*)d_in[5];
    const float* aw1  = (const float*)d_in[6];
    const float* mean = (const float*)d_in[7];
    const float* lamp = (const float*)d_in[8];
    float* out = (float*)d_out;

    float* w   = (float*)d_ws;
    float* f0n = w;                  // 600
    float* f0t = w + 640;            // 600
    v8s*  abuf = (v8s*)(w + 1536);   // 6400 * 16 B = 102400 B
    short* tb  = (short*)(w + 32768);

    k_prep<<<25, 256, 0, stream>>>(f0, f1, f0n, f0t, abuf);
    dim3 grid(W / 8, H / 8);         // 32 x 32 = 1024 blocks
    k_fuseA<<<grid, 256, 0, stream>>>(x, f0n, abuf, mean, aw0, aw1, tb);
    k_fuseB<<<grid, 256, 0, stream>>>(tb, abuf, f0t, mean, aw0, x, y, lamp, out);
}